// Round 3
// baseline (340.624 us; speedup 1.0000x reference)
//
#include <hip/hip_runtime.h>
#include <hip/hip_cooperative_groups.h>

namespace cg = cooperative_groups;

#define POINTS 120
#define GROUPS 4
#define NTOT 33554432      // 8*64*256*256
#define NGRP 8388608       // NTOT/GROUPS
#define NBLK 1024
#define NTHR 256

typedef float f4v __attribute__((ext_vector_type(4)));

// Workspace (32-bit words):
// [0,480)    hist counts (uint), 4 groups x 120 bins (device atomics)
// [480,484)  min keys (ordered uint)
// [484,488)  max keys (ordered uint)

__device__ __forceinline__ unsigned ord_enc(float f) {
    unsigned u = __float_as_uint(f);
    return (u & 0x80000000u) ? ~u : (u | 0x80000000u);
}
__device__ __forceinline__ float ord_dec(unsigned k) {
    unsigned u = (k & 0x80000000u) ? (k ^ 0x80000000u) : ~k;
    return __uint_as_float(u);
}

__global__ __launch_bounds__(NTHR, 4) void k_fused(const float* __restrict__ data,
                                                   const float* __restrict__ params,
                                                   const float* __restrict__ ct_p,
                                                   const float* __restrict__ st_p,
                                                   unsigned* __restrict__ ws,
                                                   float* __restrict__ out) {
    __shared__ unsigned h[4][POINTS];            // per-wave hist copies
    __shared__ float s_acc[GROUPS * POINTS];     // counts -> accum (in place)
    __shared__ float s_ft[GROUPS * POINTS];
    __shared__ float s_fv[GROUPS * POINTS];
    __shared__ float s_dw[8];                    // dmin[4], width[4]
    __shared__ float s_mw[2];                    // this block's group dmin,width (hist phase)

    const int tid = threadIdx.x;
    const int bid = blockIdx.x;
    const float ct = ct_p[0];
    const int g = (bid >> 1) & 3;                // chunk = half channel-plane; group = channel & 3
    const size_t base = (size_t)bid * 32768;
    const float4* p = (const float4*)(data + base);

    // ---------- Phase A: per-group min/max ----------
    {
        float mn = 3.0e38f, mx = -3.0e38f;
        #pragma unroll 4
        for (int it = 0; it < 32; ++it) {
            float4 v = p[it * 256 + tid];
            v.x *= ct; v.y *= ct; v.z *= ct; v.w *= ct;
            mn = fminf(mn, fminf(fminf(v.x, v.y), fminf(v.z, v.w)));
            mx = fmaxf(mx, fmaxf(fmaxf(v.x, v.y), fmaxf(v.z, v.w)));
        }
        for (int off = 32; off; off >>= 1) {
            mn = fminf(mn, __shfl_xor(mn, off));
            mx = fmaxf(mx, __shfl_xor(mx, off));
        }
        __shared__ float smn[4], smx[4];
        int wid = tid >> 6;
        if ((tid & 63) == 0) { smn[wid] = mn; smx[wid] = mx; }
        __syncthreads();
        if (tid == 0) {
            mn = fminf(fminf(smn[0], smn[1]), fminf(smn[2], smn[3]));
            mx = fmaxf(fmaxf(smx[0], smx[1]), fmaxf(smx[2], smx[3]));
            atomicMin(&ws[480 + g], ord_enc(mn));
            atomicMax(&ws[484 + g], ord_enc(mx));
        }
    }
    cg::this_grid().sync();

    // ---------- Phase B: histogram (per-wave LDS copies) ----------
    {
        for (int i = tid; i < 4 * POINTS; i += NTHR) ((unsigned*)h)[i] = 0u;
        if (tid == 0) {
            float dmin = ord_dec(__hip_atomic_load(&ws[480 + g], __ATOMIC_RELAXED, __HIP_MEMORY_SCOPE_AGENT));
            float dmax = ord_dec(__hip_atomic_load(&ws[484 + g], __ATOMIC_RELAXED, __HIP_MEMORY_SCOPE_AGENT));
            s_mw[0] = dmin;
            s_mw[1] = (dmax - dmin) / (float)POINTS;
        }
        __syncthreads();
        const float dmin = s_mw[0];
        const float inv_w = 1.0f / s_mw[1];
        const int wid = tid >> 6;
        for (int it = 0; it < 32; ++it) {
            float4 v = p[it * 256 + tid];
            float a[4] = {v.x, v.y, v.z, v.w};
            #pragma unroll
            for (int j = 0; j < 4; ++j) {
                float d = a[j] * ct;
                int b = (int)floorf((d - dmin) * inv_w);
                b = min(max(b, 0), POINTS - 1);
                atomicAdd(&h[wid][b], 1u);
            }
        }
        __syncthreads();
        for (int i = tid; i < POINTS; i += NTHR) {
            unsigned s = h[0][i] + h[1][i] + h[2][i] + h[3][i];
            if (s) atomicAdd(&ws[g * POINTS + i], s);
        }
    }
    cg::this_grid().sync();

    // ---------- Phase C: curves, redundantly per block (all in LDS) ----------
    {
        for (int i = tid; i < GROUPS * POINTS; i += NTHR)
            s_acc[i] = (float)__hip_atomic_load(&ws[i], __ATOMIC_RELAXED, __HIP_MEMORY_SCOPE_AGENT);
        if (tid < 4) {
            float dmin = ord_dec(__hip_atomic_load(&ws[480 + tid], __ATOMIC_RELAXED, __HIP_MEMORY_SCOPE_AGENT));
            float dmax = ord_dec(__hip_atomic_load(&ws[484 + tid], __ATOMIC_RELAXED, __HIP_MEMORY_SCOPE_AGENT));
            s_dw[tid] = dmin;
            s_dw[4 + tid] = (dmax - dmin) / (float)POINTS;
        }
        __syncthreads();
        if (tid < 4) {                            // serial cumsum per group (matches ref order)
            float c = 0.f;
            for (int k = 0; k < POINTS; ++k) {
                c += s_acc[tid * POINTS + k] / (float)NGRP;
                s_acc[tid * POINTS + k] = c * (float)(POINTS - 1);
            }
        }
        __syncthreads();
        if (tid < POINTS) {
            float v = (float)tid;                 // xnew
            #pragma unroll
            for (int gg = 0; gg < GROUPS; ++gg) {
                const float* acc = s_acc + gg * POINTS;
                int cnt = 0;
                for (int k = 0; k < POINTS; ++k) cnt += (acc[k] < v) ? 1 : 0;
                int ind = min(max(cnt - 1, 0), POINTS - 2);
                float x0 = acc[ind], x1 = acc[ind + 1];
                float tt = (v - x0) / (x1 - x0);
                const float* th = params + gg * POINTS;
                const float* ve = params + GROUPS * POINTS + gg * POINTS;
                s_ft[gg * POINTS + tid] = th[ind] + tt * (th[ind + 1] - th[ind]);
                s_fv[gg * POINTS + tid] = ve[ind] + tt * (ve[ind + 1] - ve[ind]);
            }
        }
        __syncthreads();
    }

    // ---------- Phase D: apply + permuted write ----------
    {
        const float st = st_p[0];
        const int M = NTOT / 4;
        for (int m = bid * NTHR + tid; m < M; m += NBLK * NTHR) {
            int b  = m >> 20;
            int cp = (m >> 16) & 15;
            int hw = m & 65535;
            size_t ib = ((size_t)(b * 64 + cp * 4) << 16) + hw;
            float r[4];
            #pragma unroll
            for (int gg = 0; gg < 4; ++gg) {
                float v = data[ib + ((size_t)gg << 16)] * ct;
                float dmin = s_dw[gg], width = s_dw[4 + gg];
                const float* acc = s_acc + gg * POINTS;
                float u = (v - dmin) / width - 0.5f;
                int ind = min(max((int)floorf(u), 0), POINTS - 2);
                float c0 = dmin + width * ((float)ind + 0.5f);
                float index = acc[ind] + (v - c0) / width * (acc[ind + 1] - acc[ind]);
                int beg = min(max((int)floorf(index), 0), POINTS - 1);
                float pos = index - (float)beg;
                int end = min(beg + 1, POINTS - 1);
                float theta = (1.f - pos) * s_ft[gg * POINTS + beg] + pos * s_ft[gg * POINTS + end];
                float velo  = (1.f - pos) * s_fv[gg * POINTS + beg] + pos * s_fv[gg * POINTS + end];
                float ds = velo * 0.01f;
                float sth, cth;
                __sincosf(theta, &sth, &cth);
                r[gg] = (v * (1.f + ds * sth) + ds * cth) * st;
            }
            f4v o = {r[0], r[1], r[2], r[3]};
            __builtin_nontemporal_store(o, (f4v*)(out + (size_t)m * 4));
        }
    }
}

extern "C" void kernel_launch(void* const* d_in, const int* in_sizes, int n_in,
                              void* d_out, int out_size, void* d_ws, size_t ws_size,
                              hipStream_t stream) {
    const float* data = (const float*)d_in[0];
    const float* params = (const float*)d_in[1];
    const float* ct = (const float*)d_in[2];
    const float* st = (const float*)d_in[3];
    unsigned* ws = (unsigned*)d_ws;
    float* outp = (float*)d_out;

    (void)hipMemsetAsync(ws, 0, 480 * sizeof(unsigned), stream);            // hist counts = 0
    (void)hipMemsetAsync(ws + 480, 0xFF, 4 * sizeof(unsigned), stream);     // min keys = 0xFFFFFFFF
    (void)hipMemsetAsync(ws + 484, 0, 4 * sizeof(unsigned), stream);        // max keys = 0

    void* args[] = {(void*)&data, (void*)&params, (void*)&ct, (void*)&st, (void*)&ws, (void*)&outp};
    (void)hipLaunchCooperativeKernel((const void*)k_fused, dim3(NBLK), dim3(NTHR), args, 0, stream);
}

// Round 4
// 223.973 us; speedup vs baseline: 1.5208x; 1.5208x over previous
//
#include <hip/hip_runtime.h>

#define POINTS 120
#define GROUPS 4
#define NTOT 33554432      // 8*64*256*256
#define NGRP 8388608       // NTOT/GROUPS
#define NBLK 1024
#define NTHR 256

typedef float f4v __attribute__((ext_vector_type(4)));

// Workspace (32-bit words):
// [0,480)     hist counts (uint), 4 groups x 120 bins (device atomics)
// [480,484)   min keys (ordered uint)
// [484,488)   max keys (ordered uint)
// [488]       done counter (last-block detection)
// [496,976)   accum (float) 4x120
// [976,1456)  frame_theta (float) 4x120
// [1456,1936) frame_velo (float) 4x120
// [1936,1940) dmin per group (float)
// [1940,1944) width per group (float)

__device__ __forceinline__ unsigned ord_enc(float f) {
    unsigned u = __float_as_uint(f);
    return (u & 0x80000000u) ? ~u : (u | 0x80000000u);
}
__device__ __forceinline__ float ord_dec(unsigned k) {
    unsigned u = (k & 0x80000000u) ? (k ^ 0x80000000u) : ~k;
    return __uint_as_float(u);
}

// grid = 1024 blocks, each covers 32768 contiguous elements (half a channel plane)
__global__ __launch_bounds__(256) void k_minmax(const float* __restrict__ data,
                                                const float* __restrict__ ct_p,
                                                unsigned* __restrict__ ws) {
    const float ct = ct_p[0];
    const int g = (blockIdx.x >> 1) & 3;   // plane = blockIdx/2; group = plane & 3 = channel & 3
    const size_t base = (size_t)blockIdx.x * 32768;
    const float4* p = (const float4*)(data + base);
    float mn = 3.0e38f, mx = -3.0e38f;
    #pragma unroll 4
    for (int it = 0; it < 32; ++it) {
        float4 v = p[it * 256 + threadIdx.x];
        v.x *= ct; v.y *= ct; v.z *= ct; v.w *= ct;
        mn = fminf(mn, fminf(fminf(v.x, v.y), fminf(v.z, v.w)));
        mx = fmaxf(mx, fmaxf(fmaxf(v.x, v.y), fmaxf(v.z, v.w)));
    }
    for (int off = 32; off; off >>= 1) {
        mn = fminf(mn, __shfl_xor(mn, off));
        mx = fmaxf(mx, __shfl_xor(mx, off));
    }
    __shared__ float smn[4], smx[4];
    int wid = threadIdx.x >> 6;
    if ((threadIdx.x & 63) == 0) { smn[wid] = mn; smx[wid] = mx; }
    __syncthreads();
    if (threadIdx.x == 0) {
        mn = fminf(fminf(smn[0], smn[1]), fminf(smn[2], smn[3]));
        mx = fmaxf(fmaxf(smx[0], smx[1]), fmaxf(smx[2], smx[3]));
        atomicMin(&ws[480 + g], ord_enc(mn));
        atomicMax(&ws[484 + g], ord_enc(mx));
    }
}

// grid = 1024 blocks; histogram with per-wave LDS copies; last block builds curves
__global__ __launch_bounds__(256) void k_hist_curves(const float* __restrict__ data,
                                                     const float* __restrict__ params,
                                                     const float* __restrict__ ct_p,
                                                     unsigned* __restrict__ ws) {
    float* wsf = (float*)ws;
    __shared__ unsigned h[4][POINTS];
    __shared__ float s_mw[2];
    __shared__ bool s_last;
    const int tid = threadIdx.x;
    const float ct = ct_p[0];
    const int g = (blockIdx.x >> 1) & 3;

    for (int i = tid; i < 4 * POINTS; i += NTHR) ((unsigned*)h)[i] = 0u;
    if (tid == 0) {
        float dmin = ord_dec(__hip_atomic_load(&ws[480 + g], __ATOMIC_RELAXED, __HIP_MEMORY_SCOPE_AGENT));
        float dmax = ord_dec(__hip_atomic_load(&ws[484 + g], __ATOMIC_RELAXED, __HIP_MEMORY_SCOPE_AGENT));
        s_mw[0] = dmin;
        s_mw[1] = (dmax - dmin) / (float)POINTS;
    }
    __syncthreads();
    const float dmin_b = s_mw[0];
    const float inv_w = 1.0f / s_mw[1];
    const int wid = tid >> 6;
    const size_t base = (size_t)blockIdx.x * 32768;
    const float4* p = (const float4*)(data + base);
    for (int it = 0; it < 32; ++it) {
        float4 v = p[it * 256 + tid];
        float a[4] = {v.x, v.y, v.z, v.w};
        #pragma unroll
        for (int j = 0; j < 4; ++j) {
            float d = a[j] * ct;
            int b = (int)floorf((d - dmin_b) * inv_w);
            b = min(max(b, 0), POINTS - 1);
            atomicAdd(&h[wid][b], 1u);
        }
    }
    __syncthreads();
    for (int i = tid; i < POINTS; i += NTHR) {
        unsigned s = h[0][i] + h[1][i] + h[2][i] + h[3][i];
        if (s) atomicAdd(&ws[g * POINTS + i], s);
    }

    // ---- last-block: build accum + warped curves ----
    __threadfence();                               // my hist adds visible before counter bump
    if (tid == 0) s_last = (atomicAdd(&ws[488], 1u) == NBLK - 1);
    __syncthreads();
    if (!s_last) return;
    __threadfence();                               // acquire: see all blocks' hist adds

    __shared__ float s_acc[GROUPS * POINTS];
    for (int i = tid; i < GROUPS * POINTS; i += NTHR)
        s_acc[i] = (float)__hip_atomic_load(&ws[i], __ATOMIC_RELAXED, __HIP_MEMORY_SCOPE_AGENT);
    __shared__ float s_dw[8];
    if (tid < 4) {
        float dmin = ord_dec(__hip_atomic_load(&ws[480 + tid], __ATOMIC_RELAXED, __HIP_MEMORY_SCOPE_AGENT));
        float dmax = ord_dec(__hip_atomic_load(&ws[484 + tid], __ATOMIC_RELAXED, __HIP_MEMORY_SCOPE_AGENT));
        s_dw[tid] = dmin;
        s_dw[4 + tid] = (dmax - dmin) / (float)POINTS;
        wsf[1936 + tid] = dmin;
        wsf[1940 + tid] = s_dw[4 + tid];
    }
    __syncthreads();
    if (tid < 4) {                                 // serial cumsum per group (matches ref order)
        float c = 0.f;
        for (int k = 0; k < POINTS; ++k) {
            c += s_acc[tid * POINTS + k] / (float)NGRP;
            float a = c * (float)(POINTS - 1);
            s_acc[tid * POINTS + k] = a;
            wsf[496 + tid * POINTS + k] = a;
        }
    }
    __syncthreads();
    if (tid < POINTS) {
        float v = (float)tid;                      // xnew
        #pragma unroll
        for (int gg = 0; gg < GROUPS; ++gg) {
            const float* acc = s_acc + gg * POINTS;
            int cnt = 0;
            for (int k = 0; k < POINTS; ++k) cnt += (acc[k] < v) ? 1 : 0;
            int ind = min(max(cnt - 1, 0), POINTS - 2);
            float x0 = acc[ind], x1 = acc[ind + 1];
            float tt = (v - x0) / (x1 - x0);
            const float* th = params + gg * POINTS;
            const float* ve = params + GROUPS * POINTS + gg * POINTS;
            wsf[976  + gg * POINTS + tid] = th[ind] + tt * (th[ind + 1] - th[ind]);
            wsf[1456 + gg * POINTS + tid] = ve[ind] + tt * (ve[ind + 1] - ve[ind]);
        }
    }
}

// grid-stride over m in [0, NTOT/4); each thread produces out[4m..4m+3] as one float4
__global__ __launch_bounds__(256) void k_apply(const float* __restrict__ data,
                                               const float* __restrict__ ct_p,
                                               const float* __restrict__ st_p,
                                               const unsigned* __restrict__ wsu,
                                               float* __restrict__ out) {
    const float* wsf = (const float*)wsu;
    __shared__ float s_acc[GROUPS * POINTS];
    __shared__ float s_ft[GROUPS * POINTS];
    __shared__ float s_fv[GROUPS * POINTS];
    __shared__ float s_dw[8];   // dmin[4], width[4]
    for (int i = threadIdx.x; i < GROUPS * POINTS; i += 256) {
        s_acc[i] = wsf[496 + i];
        s_ft[i]  = wsf[976 + i];
        s_fv[i]  = wsf[1456 + i];
    }
    if (threadIdx.x < 8) s_dw[threadIdx.x] = wsf[1936 + threadIdx.x];
    __syncthreads();

    const float ct = ct_p[0], st = st_p[0];
    const int M = NTOT / 4;
    for (int m = blockIdx.x * 256 + threadIdx.x; m < M; m += gridDim.x * 256) {
        int b  = m >> 20;          // 16*65536 m's per batch
        int cp = (m >> 16) & 15;   // channel-within-group index
        int hw = m & 65535;
        size_t ib = ((size_t)(b * 64 + cp * 4) << 16) + hw;
        float r[4];
        #pragma unroll
        for (int gg = 0; gg < 4; ++gg) {
            float v = data[ib + ((size_t)gg << 16)] * ct;
            float dmin = s_dw[gg], width = s_dw[4 + gg];
            const float* acc = s_acc + gg * POINTS;
            float u = (v - dmin) / width - 0.5f;
            int ind = min(max((int)floorf(u), 0), POINTS - 2);
            float c0 = dmin + width * ((float)ind + 0.5f);
            float index = acc[ind] + (v - c0) / width * (acc[ind + 1] - acc[ind]);
            int beg = min(max((int)floorf(index), 0), POINTS - 1);
            float pos = index - (float)beg;
            int end = min(beg + 1, POINTS - 1);
            float theta = (1.f - pos) * s_ft[gg * POINTS + beg] + pos * s_ft[gg * POINTS + end];
            float velo  = (1.f - pos) * s_fv[gg * POINTS + beg] + pos * s_fv[gg * POINTS + end];
            float ds = velo * 0.01f;
            float sth, cth;
            __sincosf(theta, &sth, &cth);
            r[gg] = (v * (1.f + ds * sth) + ds * cth) * st;
        }
        f4v o = {r[0], r[1], r[2], r[3]};
        __builtin_nontemporal_store(o, (f4v*)(out + (size_t)m * 4));
    }
}

extern "C" void kernel_launch(void* const* d_in, const int* in_sizes, int n_in,
                              void* d_out, int out_size, void* d_ws, size_t ws_size,
                              hipStream_t stream) {
    const float* data = (const float*)d_in[0];
    const float* params = (const float*)d_in[1];
    const float* ct = (const float*)d_in[2];
    const float* st = (const float*)d_in[3];
    unsigned* ws = (unsigned*)d_ws;
    float* outp = (float*)d_out;

    (void)hipMemsetAsync(ws, 0, 480 * sizeof(unsigned), stream);         // hist counts = 0
    (void)hipMemsetAsync(ws + 480, 0xFF, 4 * sizeof(unsigned), stream);  // min keys
    (void)hipMemsetAsync(ws + 484, 0, 8 * sizeof(unsigned), stream);     // max keys + done counter

    hipLaunchKernelGGL(k_minmax, dim3(NBLK), dim3(NTHR), 0, stream, data, ct, ws);
    hipLaunchKernelGGL(k_hist_curves, dim3(NBLK), dim3(NTHR), 0, stream, data, params, ct, ws);
    hipLaunchKernelGGL(k_apply, dim3(4096), dim3(NTHR), 0, stream, data, ct, st, ws, outp);
}